// Round 1
// baseline (1052.425 us; speedup 1.0000x reference)
//
#include <hip/hip_runtime.h>
#include <hip/hip_bf16.h>

#define Bb 128
#define Tt 1024
#define Nn 128
#define Ss 256
#define NEGF (-1e30f)
#define D9 9.0f   // fixed log-domain shift per active step (absorbed via c at the end)

typedef __attribute__((ext_vector_type(8))) short short8;  // 8 bf16 (4 VGPRs) — MFMA A/B frag
typedef __attribute__((ext_vector_type(4))) float f32x4;   // MFMA C/D frag

__device__ __forceinline__ short bf16b(float f) {
    __hip_bfloat16 h = __float2bfloat16(f);
    return *reinterpret_cast<short*>(&h);
}

// w-value: precomputed path reads exp(x-9) directly; fallback computes inline.
#define WV(v) (PRE ? (v) : __expf((v) - D9))

// ---- FCC per-step body (single-wave, barrier-free).
// State permutation: state s -> D slot (mt=(s&31)>>2, h=s>>5, r=s&3)
//                          -> B slot (kc=(s&31)>>3, h=s>>5, jj=s&7)
// so frag[kc] = pack(p[2kc][0..3], p[2kc+1][0..3]) is LANE-LOCAL (no LDS, no shfl).
// E is loaded once with rows/cols permuted to match (see ea[] setup).
// Freeze (t>=len) handled by one-shot snapshot at t==len-1: garbage stays
// confined to its batch column (MFMA D col c depends only on B col c).
#define FCC_STEP(t_, k_)                                                       \
    {                                                                          \
        const int t = (t_);                                                    \
        const int sl = (k_) & 3;  /* tb%8==0 -> compile-time ring slot */      \
        float p[8][4];                                                         \
        _Pragma("unroll")                                                      \
        for (int mt = 0; mt < 8; ++mt) {                                       \
            p[mt][0] = WV(xs[sl][mt][0]) * acc[mt][0];                         \
            p[mt][1] = WV(xs[sl][mt][1]) * acc[mt][1];                         \
            p[mt][2] = WV(xs[sl][mt][2]) * acc[mt][2];                         \
            p[mt][3] = WV(xs[sl][mt][3]) * acc[mt][3];                         \
        }                                                                      \
        if ((k_) == 0) { /* renorm apply: rm measured at k==7 of prev chunk */ \
            float invm = 1.0f / rm;                                            \
            c += __logf(rm);                                                   \
            _Pragma("unroll")                                                  \
            for (int mt = 0; mt < 8; ++mt) {                                   \
                p[mt][0] *= invm; p[mt][1] *= invm;                            \
                p[mt][2] *= invm; p[mt][3] *= invm;                            \
            }                                                                  \
        }                                                                      \
        if (t == len - 1) { /* snapshot: all 4 h-lanes of batch share len */   \
            float s = 0.f;                                                     \
            _Pragma("unroll")                                                  \
            for (int mt = 0; mt < 8; ++mt)                                     \
                s += (p[mt][0] + p[mt][1]) + (p[mt][2] + p[mt][3]);            \
            s += __shfl_xor(s, 16);                                            \
            s += __shfl_xor(s, 32);                                            \
            sfin = s; cfin = c;                                                \
        }                                                                      \
        _Pragma("unroll")                                                      \
        for (int kc = 0; kc < 4; ++kc) {                                       \
            short8 v;                                                          \
            v[0] = bf16b(p[2 * kc][0]);     v[1] = bf16b(p[2 * kc][1]);        \
            v[2] = bf16b(p[2 * kc][2]);     v[3] = bf16b(p[2 * kc][3]);        \
            v[4] = bf16b(p[2 * kc + 1][0]); v[5] = bf16b(p[2 * kc + 1][1]);    \
            v[6] = bf16b(p[2 * kc + 1][2]); v[7] = bf16b(p[2 * kc + 1][3]);    \
            fr[kc] = v;                                                        \
        }                                                                      \
        if ((k_) == 7) { /* renorm measure (unconditional; garbage harmless) */\
            float mm = fmaxf(fmaxf(p[0][0], p[0][1]), fmaxf(p[0][2], p[0][3]));\
            _Pragma("unroll")                                                  \
            for (int mt = 1; mt < 8; ++mt)                                     \
                mm = fmaxf(mm, fmaxf(fmaxf(p[mt][0], p[mt][1]),                \
                                     fmaxf(p[mt][2], p[mt][3])));              \
            mm = fmaxf(mm, __shfl_xor(mm, 16));                                \
            mm = fmaxf(mm, __shfl_xor(mm, 32));                                \
            rm = mm;                                                           \
        }                                                                      \
        { /* refill ring slot with row t+4 (consumed 4 steps from now) */      \
            int kk = t + 4; if (kk > Tt - 1) kk = Tt - 1;                      \
            const f32x4* src = (const f32x4*)(wb + (size_t)kk * Nn);           \
            _Pragma("unroll")                                                  \
            for (int mt = 0; mt < 8; ++mt) xs[sl][mt] = src[mt];               \
        }                                                                      \
        const f32x4 zz = {0.f, 0.f, 0.f, 0.f};                                 \
        _Pragma("unroll")                                                      \
        for (int mt = 0; mt < 8; ++mt)                                         \
            acc[mt] = __builtin_amdgcn_mfma_f32_16x16x32_bf16(ea[mt][0], fr[0], zz, 0, 0, 0); \
        _Pragma("unroll")                                                      \
        for (int kc = 1; kc < 4; ++kc) {                                       \
            _Pragma("unroll")                                                  \
            for (int mt = 0; mt < 8; ++mt)                                     \
                acc[mt] = __builtin_amdgcn_mfma_f32_16x16x32_bf16(ea[mt][kc], fr[kc], acc[mt], 0, 0, 0); \
        }                                                                      \
    }

// ---- FAC per-step body (unchanged from previous version).
#define FAC_STEP(t_, k_)                                                       \
    {                                                                          \
        const int t = (t_);                                                    \
        const int d = ((k_) + 7) & 7;                                          \
        float e0 = em[d][0], e1 = em[d][1], e2 = em[d][2], e3 = em[d][3];      \
        int tn = t + 8; if (tn > Tt - 1) tn = Tt - 1;                          \
        const float* xrow = xb + (size_t)tn * Nn;                              \
        em[d][0] = xrow[tgi[0]]; em[d][1] = xrow[tgi[1]];                      \
        em[d][2] = xrow[tgi[2]]; em[d][3] = xrow[tgi[3]];                      \
        float bup = __shfl_up(bt[3], 1);                                       \
        float prev0 = (lane == 0) ? NEGF : bup;                                \
        float nb[4];                                                           \
        {                                                                      \
            float aa = bt[0] + st[0], bb = prev0 + ntr[0];                     \
            float hi = fmaxf(aa, bb), lo = fminf(aa, bb);                      \
            nb[0] = e0 + hi + __logf(1.0f + __expf(lo - hi));                  \
        }                                                                      \
        {                                                                      \
            float aa = bt[1] + st[1], bb = bt[0] + ntr[1];                     \
            float hi = fmaxf(aa, bb), lo = fminf(aa, bb);                      \
            nb[1] = e1 + hi + __logf(1.0f + __expf(lo - hi));                  \
        }                                                                      \
        {                                                                      \
            float aa = bt[2] + st[2], bb = bt[1] + ntr[2];                     \
            float hi = fmaxf(aa, bb), lo = fminf(aa, bb);                      \
            nb[2] = e2 + hi + __logf(1.0f + __expf(lo - hi));                  \
        }                                                                      \
        {                                                                      \
            float aa = bt[3] + st[3], bb = bt[2] + ntr[3];                     \
            float hi = fmaxf(aa, bb), lo = fminf(aa, bb);                      \
            nb[3] = e3 + hi + __logf(1.0f + __expf(lo - hi));                  \
        }                                                                      \
        if (t < len) {                                                         \
            bt[0] = nb[0]; bt[1] = nb[1]; bt[2] = nb[2]; bt[3] = nb[3];        \
        }                                                                      \
    }

// W = exp(x - 9), fully parallel (256 CUs), ~128 MB traffic ≈ 25 us.
__global__ __launch_bounds__(256) void exp_w_kernel(const float* __restrict__ x,
                                                    float* __restrict__ w) {
    const size_t total  = (size_t)Bb * Tt * Nn;
    const size_t stride = (size_t)gridDim.x * 256 * 4;
    for (size_t i = ((size_t)blockIdx.x * 256 + threadIdx.x) * 4; i < total; i += stride) {
        f32x4 v = *(const f32x4*)(x + i);
        f32x4 o;
        o[0] = __expf(v[0] - D9); o[1] = __expf(v[1] - D9);
        o[2] = __expf(v[2] - D9); o[3] = __expf(v[3] - D9);
        *(f32x4*)(w + i) = o;
    }
}

// blocks 0..1:  FCC — 4 independent waves/block, 16 batches/wave, no LDS, no barriers
// blocks 2..33: FAC — 1 wave per batch, wave-synchronous
template <bool PRE>
__global__ __launch_bounds__(256, 1) void asg_main(
    const float* __restrict__ trans, const float* __restrict__ x,
    const float* __restrict__ W,
    const int* __restrict__ targets, const int* __restrict__ ilen,
    const int* __restrict__ tlen,
    float* __restrict__ fcc_out, float* __restrict__ fac_out)
{
    const int tid  = threadIdx.x;
    const int q    = tid >> 6;
    const int lane = tid & 63;

    if (blockIdx.x < 2) {
        // ================= FCC (wave-synchronous) =================
        const int h  = lane >> 4;       // lane group: owns states 32h..32h+31
        const int cc = lane & 15;       // batch column within wave
        const int wv = (blockIdx.x << 2) + q;   // 0..7
        const int b  = (wv << 4) + cc;
        const int len = ilen[b];
        const float* wb = (PRE ? W : x) + (size_t)b * Tt * Nn + 32 * h;

        // E A-frags, state-permuted: ea[mt][kc][jj] = exp(trans[srow][scol]),
        //   srow = 32*(cc>>2) + 4*mt + (cc&3)   (M-index permutation)
        //   scol = 32*h + 8*kc + jj             (K-index permutation)
        short8 ea[8][4];
        #pragma unroll
        for (int mt = 0; mt < 8; ++mt) {
            const int srow = 32 * (cc >> 2) + 4 * mt + (cc & 3);
            const float* tr = trans + (size_t)srow * Nn + 32 * h;
            #pragma unroll
            for (int kc = 0; kc < 4; ++kc) {
                short8 v;
                #pragma unroll
                for (int jj = 0; jj < 8; ++jj)
                    v[jj] = bf16b(__expf(tr[8 * kc + jj]));
                ea[mt][kc] = v;
            }
        }

        f32x4 acc[8];       // E*u result, slot (mt,r) = state 32h+4mt+r, col = batch cc
        f32x4 xs[4][8];     // w ring, depth 4: slot k&3, f4 #mt = states 32h+4mt..+3
        short8 fr[4];       // u as B-frags, chunk kc = states 32h+8kc..+7
        float c = 0.f, rm = 1.0f, sfin = 1.0f, cfin = 0.f;

        {   // t = 0: u0 = exp(x0 - 9); acc = E*u0
            const f32x4* r0 = (const f32x4*)(wb);
            float p[8][4];
            #pragma unroll
            for (int mt = 0; mt < 8; ++mt) {
                f32x4 v = r0[mt];
                p[mt][0] = WV(v[0]); p[mt][1] = WV(v[1]);
                p[mt][2] = WV(v[2]); p[mt][3] = WV(v[3]);
            }
            #pragma unroll
            for (int kc = 0; kc < 4; ++kc) {
                short8 v;
                v[0] = bf16b(p[2*kc][0]);   v[1] = bf16b(p[2*kc][1]);
                v[2] = bf16b(p[2*kc][2]);   v[3] = bf16b(p[2*kc][3]);
                v[4] = bf16b(p[2*kc+1][0]); v[5] = bf16b(p[2*kc+1][1]);
                v[6] = bf16b(p[2*kc+1][2]); v[7] = bf16b(p[2*kc+1][3]);
                fr[kc] = v;
            }
            const f32x4 zz = {0.f, 0.f, 0.f, 0.f};
            #pragma unroll
            for (int mt = 0; mt < 8; ++mt)
                acc[mt] = __builtin_amdgcn_mfma_f32_16x16x32_bf16(ea[mt][0], fr[0], zz, 0, 0, 0);
            #pragma unroll
            for (int kc = 1; kc < 4; ++kc) {
                #pragma unroll
                for (int mt = 0; mt < 8; ++mt)
                    acc[mt] = __builtin_amdgcn_mfma_f32_16x16x32_bf16(ea[mt][kc], fr[kc], acc[mt], 0, 0, 0);
            }
        }
        // preload ring rows 1..4 into slots 1,2,3,0
        #pragma unroll
        for (int k = 1; k <= 4; ++k) {
            const f32x4* rr = (const f32x4*)(wb + (size_t)k * Nn);
            #pragma unroll
            for (int mt = 0; mt < 8; ++mt) xs[k & 3][mt] = rr[mt];
        }

        // prologue t = 1..7, then 127 chunks of 8
        #pragma unroll
        for (int k = 1; k < 8; ++k) FCC_STEP(k, k)
        for (int tb = 8; tb < Tt; tb += 8) {
            #pragma unroll
            for (int k = 0; k < 8; ++k) FCC_STEP(tb + k, k)
        }

        if (h == 0) fcc_out[b] = cfin + D9 * (float)len + __logf(sfin);
    } else {
        // ================= FAC (1 wave per batch, no barriers) =================
        const int b   = ((blockIdx.x - 2) << 2) + q;
        const int len = ilen[b];
        const int tl  = tlen[b];
        const float* xb = x + (size_t)b * Tt * Nn;

        int   tgi[4];
        float st[4], ntr[4], bt[4];
        #pragma unroll
        for (int r = 0; r < 4; ++r) {
            const int s = (lane << 2) + r;
            const int tgv = targets[b * Ss + s];
            const int pg  = (s == 0) ? tgv : targets[b * Ss + s - 1];
            tgi[r] = tgv;
            st[r]  = trans[tgv * Nn + tgv];
            ntr[r] = trans[tgv * Nn + pg];
            bt[r]  = (s == 0) ? xb[tgv] : NEGF;
        }
        // em ring depth 8; em[(k-1)&7] = x[k] for k=1..8 (constant indices)
        float em[8][4];
        #pragma unroll
        for (int k = 1; k <= 8; ++k) {
            int tt = k; if (tt > Tt - 1) tt = Tt - 1;
            const float* xrow = xb + (size_t)tt * Nn;
            em[(k - 1) & 7][0] = xrow[tgi[0]];
            em[(k - 1) & 7][1] = xrow[tgi[1]];
            em[(k - 1) & 7][2] = xrow[tgi[2]];
            em[(k - 1) & 7][3] = xrow[tgi[3]];
        }

        #pragma unroll
        for (int k = 1; k < 8; ++k) FAC_STEP(k, k)
        for (int tb = 8; tb < Tt; tb += 8) {
            #pragma unroll
            for (int k = 0; k < 8; ++k) FAC_STEP(tb + k, k)
        }

        #pragma unroll
        for (int r = 0; r < 4; ++r)
            if ((lane << 2) + r == tl - 1) fac_out[b] = bt[r];
    }
}

__global__ __launch_bounds__(128) void reduce_kernel(const float* __restrict__ fcc,
                                                     const float* __restrict__ fac,
                                                     float* __restrict__ out) {
    __shared__ float r2[2];
    int tid = threadIdx.x;
    float v = fcc[tid] - fac[tid];
    #pragma unroll
    for (int o = 32; o > 0; o >>= 1) v += __shfl_xor(v, o);
    if ((tid & 63) == 0) r2[tid >> 6] = v;
    __syncthreads();
    if (tid == 0) out[0] = (r2[0] + r2[1]) * (1.0f / Bb);
}

extern "C" void kernel_launch(void* const* d_in, const int* in_sizes, int n_in,
                              void* d_out, int out_size, void* d_ws, size_t ws_size,
                              hipStream_t stream) {
    const float* trans   = (const float*)d_in[0];
    const float* x       = (const float*)d_in[1];
    const int*   targets = (const int*)d_in[2];
    const int*   ilen    = (const int*)d_in[3];
    const int*   tlen    = (const int*)d_in[4];
    float* out = (float*)d_out;

    float* fcc = (float*)d_ws;                       // B floats
    float* fac = fcc + Bb;                           // B floats
    float* W   = (float*)((char*)d_ws + 2048);       // B*T*N floats (if it fits)

    const size_t wbytes = (size_t)Bb * Tt * Nn * sizeof(float);
    const bool pre = ws_size >= wbytes + 2048;

    if (pre) {
        exp_w_kernel<<<2048, 256, 0, stream>>>(x, W);
        asg_main<true><<<2 + Bb / 4, 256, 0, stream>>>(trans, x, W, targets, ilen, tlen, fcc, fac);
    } else {
        asg_main<false><<<2 + Bb / 4, 256, 0, stream>>>(trans, x, x, targets, ilen, tlen, fcc, fac);
    }
    reduce_kernel<<<1, 128, 0, stream>>>(fcc, fac, out);
}

// Round 2
// 688.332 us; speedup vs baseline: 1.5290x; 1.5290x over previous
//
#include <hip/hip_runtime.h>
#include <hip/hip_bf16.h>

#define Bb 128
#define Tt 1024
#define Nn 128
#define Ss 256
#define NEGF (-1e30f)
#define D9 9.0f   // fixed log-domain shift per active step (absorbed via c at the end)

typedef __attribute__((ext_vector_type(8))) short short8;  // 8 bf16 (4 VGPRs) — MFMA A/B frag
typedef __attribute__((ext_vector_type(4))) float f32x4;   // MFMA C/D frag

__device__ __forceinline__ short bf16b(float f) {
    __hip_bfloat16 h = __float2bfloat16(f);
    return *reinterpret_cast<short*>(&h);
}

// Direct global->LDS DMA: lane l's 16B lands at lds + l*16 (wave-uniform dest),
// global source is per-lane. Counted in vmcnt.
__device__ __forceinline__ void load_lds16(const float* g, float* l) {
    __builtin_amdgcn_global_load_lds(
        (const __attribute__((address_space(1))) void*)g,
        (__attribute__((address_space(3))) void*)l, 16, 0, 0);
}

// w-value: precomputed path reads exp(x-9) directly; fallback computes inline.
#define WV(v) (PRE ? (v) : __expf((v) - D9))

// Issue 8 global_load_lds (one per mt) for time tn_ into ring slot sl_.
// PRE:  coalesced 1KB per instruction from the permuted Wp layout.
// !PRE: per-lane gather from x (slow TA path, correct fallback).
#define STAGE(tn_, sl_)                                                        \
    {                                                                          \
        int tn = (tn_); if (tn > Tt - 1) tn = Tt - 1;                          \
        const float* gb = wbase + (size_t)tn * TSTR;                           \
        _Pragma("unroll")                                                      \
        for (int mt = 0; mt < 8; ++mt)                                         \
            load_lds16(gb + mt * MSTR, &wl[sl_][mt * 256]);                    \
    }

// ---- FCC per-step body (single wave, no barriers, LDS staging ring).
// Ring: 8 slots x 8KB; slot for time t = t&7 (compile-time: t = tb+k, tb%8==0).
// Issue-ahead 7: step t refills slot (k+7)&7 with time t+7 (consumed last step).
// vmcnt discipline: 56 loads outstanding steady-state; vmcnt(48) retires the
// oldest 8 = exactly this step's slot (FIFO, m135 semantics). Never drains.
#define FCC_STEP(t_, k_)                                                       \
    {                                                                          \
        const int t = (t_);                                                    \
        const int sl = (k_) & 7;                                               \
        asm volatile("s_waitcnt vmcnt(48)" ::: "memory");                      \
        float p[8][4];                                                         \
        _Pragma("unroll")                                                      \
        for (int mt = 0; mt < 8; ++mt) {                                       \
            f32x4 w4 = *(const f32x4*)&wl[sl][mt * 256 + (lane << 2)];         \
            p[mt][0] = WV(w4[0]) * acc[mt][0];                                 \
            p[mt][1] = WV(w4[1]) * acc[mt][1];                                 \
            p[mt][2] = WV(w4[2]) * acc[mt][2];                                 \
            p[mt][3] = WV(w4[3]) * acc[mt][3];                                 \
        }                                                                      \
        STAGE(t + 7, ((k_) + 7) & 7)                                           \
        if ((k_) == 0) { /* renorm apply: rm measured at k==7 of prev chunk */ \
            float invm = 1.0f / rm;                                            \
            c += __logf(rm);                                                   \
            _Pragma("unroll")                                                  \
            for (int mt = 0; mt < 8; ++mt) {                                   \
                p[mt][0] *= invm; p[mt][1] *= invm;                            \
                p[mt][2] *= invm; p[mt][3] *= invm;                            \
            }                                                                  \
        }                                                                      \
        if (t == len - 1) { /* snapshot: the 4 h-lanes of a batch share len */ \
            float s = 0.f;                                                     \
            _Pragma("unroll")                                                  \
            for (int mt = 0; mt < 8; ++mt)                                     \
                s += (p[mt][0] + p[mt][1]) + (p[mt][2] + p[mt][3]);            \
            s += __shfl_xor(s, 16);                                            \
            s += __shfl_xor(s, 32);                                            \
            sfin = s; cfin = c;                                                \
        }                                                                      \
        _Pragma("unroll")                                                      \
        for (int kc = 0; kc < 4; ++kc) {                                       \
            short8 v;                                                          \
            v[0] = bf16b(p[2 * kc][0]);     v[1] = bf16b(p[2 * kc][1]);        \
            v[2] = bf16b(p[2 * kc][2]);     v[3] = bf16b(p[2 * kc][3]);        \
            v[4] = bf16b(p[2 * kc + 1][0]); v[5] = bf16b(p[2 * kc + 1][1]);    \
            v[6] = bf16b(p[2 * kc + 1][2]); v[7] = bf16b(p[2 * kc + 1][3]);    \
            fr[kc] = v;                                                        \
        }                                                                      \
        if ((k_) == 7) { /* renorm measure (unconditional; garbage harmless) */\
            float mm = fmaxf(fmaxf(p[0][0], p[0][1]), fmaxf(p[0][2], p[0][3]));\
            _Pragma("unroll")                                                  \
            for (int mt = 1; mt < 8; ++mt)                                     \
                mm = fmaxf(mm, fmaxf(fmaxf(p[mt][0], p[mt][1]),                \
                                     fmaxf(p[mt][2], p[mt][3])));              \
            mm = fmaxf(mm, __shfl_xor(mm, 16));                                \
            mm = fmaxf(mm, __shfl_xor(mm, 32));                                \
            rm = mm;                                                           \
        }                                                                      \
        const f32x4 zz = {0.f, 0.f, 0.f, 0.f};                                 \
        _Pragma("unroll")                                                      \
        for (int mt = 0; mt < 8; ++mt)                                         \
            acc[mt] = __builtin_amdgcn_mfma_f32_16x16x32_bf16(ea[mt][0], fr[0], zz, 0, 0, 0); \
        _Pragma("unroll")                                                      \
        for (int kc = 1; kc < 4; ++kc) {                                       \
            _Pragma("unroll")                                                  \
            for (int mt = 0; mt < 8; ++mt)                                     \
                acc[mt] = __builtin_amdgcn_mfma_f32_16x16x32_bf16(ea[mt][kc], fr[kc], acc[mt], 0, 0, 0); \
        }                                                                      \
    }

// ---- FAC per-step body (unchanged).
#define FAC_STEP(t_, k_)                                                       \
    {                                                                          \
        const int t = (t_);                                                    \
        const int d = ((k_) + 7) & 7;                                          \
        float e0 = em[d][0], e1 = em[d][1], e2 = em[d][2], e3 = em[d][3];      \
        int tn = t + 8; if (tn > Tt - 1) tn = Tt - 1;                          \
        const float* xrow = xb + (size_t)tn * Nn;                              \
        em[d][0] = xrow[tgi[0]]; em[d][1] = xrow[tgi[1]];                      \
        em[d][2] = xrow[tgi[2]]; em[d][3] = xrow[tgi[3]];                      \
        float bup = __shfl_up(bt[3], 1);                                       \
        float prev0 = (lane == 0) ? NEGF : bup;                                \
        float nb[4];                                                           \
        {                                                                      \
            float aa = bt[0] + st[0], bb = prev0 + ntr[0];                     \
            float hi = fmaxf(aa, bb), lo = fminf(aa, bb);                      \
            nb[0] = e0 + hi + __logf(1.0f + __expf(lo - hi));                  \
        }                                                                      \
        {                                                                      \
            float aa = bt[1] + st[1], bb = bt[0] + ntr[1];                     \
            float hi = fmaxf(aa, bb), lo = fminf(aa, bb);                      \
            nb[1] = e1 + hi + __logf(1.0f + __expf(lo - hi));                  \
        }                                                                      \
        {                                                                      \
            float aa = bt[2] + st[2], bb = bt[1] + ntr[2];                     \
            float hi = fmaxf(aa, bb), lo = fminf(aa, bb);                      \
            nb[2] = e2 + hi + __logf(1.0f + __expf(lo - hi));                  \
        }                                                                      \
        {                                                                      \
            float aa = bt[3] + st[3], bb = bt[2] + ntr[3];                     \
            float hi = fmaxf(aa, bb), lo = fminf(aa, bb);                      \
            nb[3] = e3 + hi + __logf(1.0f + __expf(lo - hi));                  \
        }                                                                      \
        if (t < len) {                                                         \
            bt[0] = nb[0]; bt[1] = nb[1]; bt[2] = nb[2]; bt[3] = nb[3];        \
        }                                                                      \
    }

// Wp[((t*8 + wv)*8 + mt)*256 + lane*4 + r] = exp(x[b][t][s] - 9)
//   with b = wv*16 + (lane&15), s = 32*(lane>>4) + 4*mt + r.
// Reads coalesced (linear over x), writes 16B-granule scatter (fire-and-forget).
__global__ __launch_bounds__(256) void exp_w_kernel(const float* __restrict__ x,
                                                    float* __restrict__ w) {
    const int nf4 = Bb * Tt * Nn / 4;
    const int stride = gridDim.x * 256;
    for (int f = blockIdx.x * 256 + threadIdx.x; f < nf4; f += stride) {
        f32x4 v = *(const f32x4*)(x + 4 * (size_t)f);
        const int s4 = f & 31;            // N/4 = 32 float4 per row
        const int t  = (f >> 5) & (Tt - 1);
        const int b  = f >> 15;           // f / (32*1024)
        const int h  = s4 >> 3;           // (4*s4)>>5
        const int mt = s4 & 7;            // ((4*s4)&31)>>2
        const int lanep = (h << 4) + (b & 15);
        const int wv = b >> 4;
        const size_t o = ((((size_t)t * 8 + wv) * 8 + mt) * 64 + lanep) * 4;
        f32x4 r;
        r[0] = __expf(v[0] - D9); r[1] = __expf(v[1] - D9);
        r[2] = __expf(v[2] - D9); r[3] = __expf(v[3] - D9);
        *(f32x4*)(w + o) = r;
    }
}

// blocks 0..7:  q0 = FCC wave (16 batches, own CU/TA/LDS), q1..3 = FAC (3 batches)
// blocks 8..33: 4 FAC waves each (4 batches)
template <bool PRE>
__global__ __launch_bounds__(256, 1) void asg_main(
    const float* __restrict__ trans, const float* __restrict__ x,
    const float* __restrict__ Wp,
    const int* __restrict__ targets, const int* __restrict__ ilen,
    const int* __restrict__ tlen,
    float* __restrict__ fcc_out, float* __restrict__ fac_out)
{
    __shared__ __align__(16) float wl[8][2048];   // 64 KiB staging ring (FCC wave only)

    const int tid  = threadIdx.x;
    const int q    = tid >> 6;
    const int lane = tid & 63;

    if (blockIdx.x < 8 && q == 0) {
        // ================= FCC (wave-synchronous) =================
        const int h  = lane >> 4;       // lane group: owns states 32h..32h+31
        const int cc = lane & 15;       // batch column within wave
        const int wv = blockIdx.x;      // 0..7
        const int b  = (wv << 4) + cc;
        const int len = ilen[b];

        constexpr int TSTR = PRE ? 16384 : Nn;   // floats per t-step in source
        constexpr int MSTR = PRE ? 256 : 4;      // floats per mt in source
        const float* wbase = PRE ? (Wp + (size_t)wv * 2048 + (lane << 2))
                                 : (x + (size_t)b * (Tt * Nn) + 32 * h);

        // E A-frags, state-permuted: ea[mt][kc][jj] = exp(trans[srow][scol]),
        //   srow = 32*(cc>>2) + 4*mt + (cc&3)   (M-index permutation)
        //   scol = 32*h + 8*kc + jj             (K-index permutation)
        short8 ea[8][4];
        #pragma unroll
        for (int mt = 0; mt < 8; ++mt) {
            const int srow = 32 * (cc >> 2) + 4 * mt + (cc & 3);
            const float* tr = trans + (size_t)srow * Nn + 32 * h;
            #pragma unroll
            for (int kc = 0; kc < 4; ++kc) {
                short8 v;
                #pragma unroll
                for (int jj = 0; jj < 8; ++jj)
                    v[jj] = bf16b(__expf(tr[8 * kc + jj]));
                ea[mt][kc] = v;
            }
        }

        f32x4 acc[8];       // E*u, slot (mt,r) = state 32h+4mt+r, col = batch cc
        short8 fr[4];       // u as B-frags, chunk kc = states 32h+8kc..+7
        float c = 0.f, rm = 1.0f, sfin = 1.0f, cfin = 0.f;

        {   // t = 0: u0 = exp(x0 - 9); acc = E*u0  (register loads, drained here)
            float p[8][4];
            #pragma unroll
            for (int mt = 0; mt < 8; ++mt) {
                f32x4 v = *(const f32x4*)(wbase + mt * MSTR);
                p[mt][0] = WV(v[0]); p[mt][1] = WV(v[1]);
                p[mt][2] = WV(v[2]); p[mt][3] = WV(v[3]);
            }
            #pragma unroll
            for (int kc = 0; kc < 4; ++kc) {
                short8 v;
                v[0] = bf16b(p[2*kc][0]);   v[1] = bf16b(p[2*kc][1]);
                v[2] = bf16b(p[2*kc][2]);   v[3] = bf16b(p[2*kc][3]);
                v[4] = bf16b(p[2*kc+1][0]); v[5] = bf16b(p[2*kc+1][1]);
                v[6] = bf16b(p[2*kc+1][2]); v[7] = bf16b(p[2*kc+1][3]);
                fr[kc] = v;
            }
            const f32x4 zz = {0.f, 0.f, 0.f, 0.f};
            #pragma unroll
            for (int mt = 0; mt < 8; ++mt)
                acc[mt] = __builtin_amdgcn_mfma_f32_16x16x32_bf16(ea[mt][0], fr[0], zz, 0, 0, 0);
            #pragma unroll
            for (int kc = 1; kc < 4; ++kc) {
                #pragma unroll
                for (int mt = 0; mt < 8; ++mt)
                    acc[mt] = __builtin_amdgcn_mfma_f32_16x16x32_bf16(ea[mt][kc], fr[kc], acc[mt], 0, 0, 0);
            }
        }

        // prologue staging: t = 1..7 into slots 1..7 (56 loads outstanding)
        #pragma unroll
        for (int tt = 1; tt <= 7; ++tt) STAGE(tt, tt)

        // steps t = 1..7, then 127 chunks of 8 (t = 8..1023)
        #pragma unroll
        for (int k = 1; k < 8; ++k) FCC_STEP(k, k)
        for (int tb = 8; tb < Tt; tb += 8) {
            #pragma unroll
            for (int k = 0; k < 8; ++k) FCC_STEP(tb + k, k)
        }

        if (lane < 16)
            fcc_out[(wv << 4) + lane] = cfin + D9 * (float)len + __logf(sfin);
    } else {
        // ================= FAC (1 wave per batch, no barriers) =================
        const int fid = (blockIdx.x < 8) ? (104 + blockIdx.x * 3 + (q - 1))
                                         : (((blockIdx.x - 8) << 2) + q);
        const int b   = fid;
        const int len = ilen[b];
        const int tl  = tlen[b];
        const float* xb = x + (size_t)b * Tt * Nn;

        int   tgi[4];
        float st[4], ntr[4], bt[4];
        #pragma unroll
        for (int r = 0; r < 4; ++r) {
            const int s = (lane << 2) + r;
            const int tgv = targets[b * Ss + s];
            const int pg  = (s == 0) ? tgv : targets[b * Ss + s - 1];
            tgi[r] = tgv;
            st[r]  = trans[tgv * Nn + tgv];
            ntr[r] = trans[tgv * Nn + pg];
            bt[r]  = (s == 0) ? xb[tgv] : NEGF;
        }
        // em ring depth 8; em[(k-1)&7] = x[k] for k=1..8 (constant indices)
        float em[8][4];
        #pragma unroll
        for (int k = 1; k <= 8; ++k) {
            int tt = k; if (tt > Tt - 1) tt = Tt - 1;
            const float* xrow = xb + (size_t)tt * Nn;
            em[(k - 1) & 7][0] = xrow[tgi[0]];
            em[(k - 1) & 7][1] = xrow[tgi[1]];
            em[(k - 1) & 7][2] = xrow[tgi[2]];
            em[(k - 1) & 7][3] = xrow[tgi[3]];
        }

        #pragma unroll
        for (int k = 1; k < 8; ++k) FAC_STEP(k, k)
        for (int tb = 8; tb < Tt; tb += 8) {
            #pragma unroll
            for (int k = 0; k < 8; ++k) FAC_STEP(tb + k, k)
        }

        #pragma unroll
        for (int r = 0; r < 4; ++r)
            if ((lane << 2) + r == tl - 1) fac_out[b] = bt[r];
    }
}

__global__ __launch_bounds__(128) void reduce_kernel(const float* __restrict__ fcc,
                                                     const float* __restrict__ fac,
                                                     float* __restrict__ out) {
    __shared__ float r2[2];
    int tid = threadIdx.x;
    float v = fcc[tid] - fac[tid];
    #pragma unroll
    for (int o = 32; o > 0; o >>= 1) v += __shfl_xor(v, o);
    if ((tid & 63) == 0) r2[tid >> 6] = v;
    __syncthreads();
    if (tid == 0) out[0] = (r2[0] + r2[1]) * (1.0f / Bb);
}

extern "C" void kernel_launch(void* const* d_in, const int* in_sizes, int n_in,
                              void* d_out, int out_size, void* d_ws, size_t ws_size,
                              hipStream_t stream) {
    const float* trans   = (const float*)d_in[0];
    const float* x       = (const float*)d_in[1];
    const int*   targets = (const int*)d_in[2];
    const int*   ilen    = (const int*)d_in[3];
    const int*   tlen    = (const int*)d_in[4];
    float* out = (float*)d_out;

    float* fcc = (float*)d_ws;                       // B floats
    float* fac = fcc + Bb;                           // B floats
    float* Wp  = (float*)((char*)d_ws + 2048);       // B*T*N floats (if it fits)

    const size_t wbytes = (size_t)Bb * Tt * Nn * sizeof(float);
    const bool pre = ws_size >= wbytes + 2048;

    if (pre) {
        exp_w_kernel<<<2048, 256, 0, stream>>>(x, Wp);
        asg_main<true><<<34, 256, 0, stream>>>(trans, x, Wp, targets, ilen, tlen, fcc, fac);
    } else {
        asg_main<false><<<34, 256, 0, stream>>>(trans, x, x, targets, ilen, tlen, fcc, fac);
    }
    reduce_kernel<<<1, 128, 0, stream>>>(fcc, fac, out);
}

// Round 3
// 682.597 us; speedup vs baseline: 1.5418x; 1.0084x over previous
//
#include <hip/hip_runtime.h>
#include <hip/hip_bf16.h>

#define Bb 128
#define Tt 1024
#define Nn 128
#define Ss 256
#define NEGF (-1e30f)
#define D9 9.0f   // fixed log-domain shift per active step (absorbed via c at the end)

typedef __attribute__((ext_vector_type(8))) short short8;  // 8 bf16 (4 VGPRs) — MFMA A/B frag
typedef __attribute__((ext_vector_type(4))) float f32x4;   // MFMA C/D frag

__device__ __forceinline__ short bf16b(float f) {
    __hip_bfloat16 h = __float2bfloat16(f);
    return *reinterpret_cast<short*>(&h);
}

// Single-instruction packed f32->bf16 (RNE). dst.lo = bf16(lo), dst.hi = bf16(hi).
// __float2bfloat16 expands to a ~7-op bit-twiddle; x32/step on ONE in-order wave
// was the round-2 bottleneck (VALUBusy arithmetic: ~400 VALU instr/step).
__device__ __forceinline__ unsigned int cvt_pk_bf16(float lo, float hi) {
    unsigned int r;
    asm("v_cvt_pk_bf16_f32 %0, %1, %2" : "=v"(r) : "v"(lo), "v"(hi));
    return r;
}

// w-value: precomputed path reads exp(x-9) directly; fallback computes inline.
#define WV(v) (PRE ? (v) : __expf((v) - D9))

// ---- FCC per-step body (single wave, barrier-free, register ring).
// Ring xs[4][8]: slot k&3 holds w-row t (depth-4 prefetch, ~4*350cy > HBM lat).
// PRE layout: each of the 8 refill loads is 64 lanes x 16B CONTIGUOUS (16 lines),
// vs round-1's 64-lines-per-load gather that TA-serialized at 2250 cy/step.
// Freeze (t>=len) handled by one-shot snapshot at t==len-1; garbage afterward is
// confined to its batch column and renorm keeps it finite (all values positive).
#define FCC_STEP(t_, k_)                                                       \
    {                                                                          \
        const int t = (t_);                                                    \
        const int sl = (k_) & 3;  /* tb%8==0 -> compile-time ring slot */      \
        f32x4 pv[8];                                                           \
        _Pragma("unroll")                                                      \
        for (int mt = 0; mt < 8; ++mt) {                                       \
            f32x4 w4 = xs[sl][mt];                                             \
            if (!PRE) {                                                        \
                w4[0] = __expf(w4[0] - D9); w4[1] = __expf(w4[1] - D9);        \
                w4[2] = __expf(w4[2] - D9); w4[3] = __expf(w4[3] - D9);        \
            }                                                                  \
            pv[mt] = w4 * acc[mt];   /* vector op -> v_pk_mul_f32 */           \
        }                                                                      \
        { /* refill ring slot sl with w-row t+4 (first use 4 steps away) */    \
            int tn = t + 4; if (tn > Tt - 1) tn = Tt - 1;                      \
            const float* gb = wbase + (size_t)tn * TSTR;                       \
            _Pragma("unroll")                                                  \
            for (int mt = 0; mt < 8; ++mt)                                     \
                xs[sl][mt] = *(const f32x4*)(gb + mt * MSTR);                  \
        }                                                                      \
        if ((k_) == 0) { /* renorm apply: rm measured at k==7 of prev chunk */ \
            float invm = 1.0f / rm;                                            \
            c += __logf(rm);                                                   \
            _Pragma("unroll")                                                  \
            for (int mt = 0; mt < 8; ++mt) pv[mt] = pv[mt] * invm;             \
        }                                                                      \
        if (t == len - 1) { /* snapshot: the 4 h-lanes of a batch share len */ \
            float s = 0.f;                                                     \
            _Pragma("unroll")                                                  \
            for (int mt = 0; mt < 8; ++mt)                                     \
                s += (pv[mt][0] + pv[mt][1]) + (pv[mt][2] + pv[mt][3]);        \
            s += __shfl_xor(s, 16);                                            \
            s += __shfl_xor(s, 32);                                            \
            sfin = s; cfin = c;                                                \
        }                                                                      \
        short8 fr[4];                                                          \
        _Pragma("unroll")                                                      \
        for (int kc = 0; kc < 4; ++kc) {                                       \
            union { short8 s8; unsigned int u[4]; } F;                         \
            F.u[0] = cvt_pk_bf16(pv[2 * kc][0],     pv[2 * kc][1]);            \
            F.u[1] = cvt_pk_bf16(pv[2 * kc][2],     pv[2 * kc][3]);            \
            F.u[2] = cvt_pk_bf16(pv[2 * kc + 1][0], pv[2 * kc + 1][1]);        \
            F.u[3] = cvt_pk_bf16(pv[2 * kc + 1][2], pv[2 * kc + 1][3]);        \
            fr[kc] = F.s8;                                                     \
        }                                                                      \
        if ((k_) == 7) { /* renorm measure (unconditional; garbage harmless) */\
            float mm = fmaxf(fmaxf(pv[0][0], pv[0][1]), fmaxf(pv[0][2], pv[0][3])); \
            _Pragma("unroll")                                                  \
            for (int mt = 1; mt < 8; ++mt)                                     \
                mm = fmaxf(mm, fmaxf(fmaxf(pv[mt][0], pv[mt][1]),              \
                                     fmaxf(pv[mt][2], pv[mt][3])));            \
            mm = fmaxf(mm, __shfl_xor(mm, 16));                                \
            mm = fmaxf(mm, __shfl_xor(mm, 32));                                \
            rm = mm;                                                           \
        }                                                                      \
        const f32x4 zz = {0.f, 0.f, 0.f, 0.f};                                 \
        _Pragma("unroll")                                                      \
        for (int mt = 0; mt < 8; ++mt)                                         \
            acc[mt] = __builtin_amdgcn_mfma_f32_16x16x32_bf16(ea[mt][0], fr[0], zz, 0, 0, 0); \
        _Pragma("unroll")                                                      \
        for (int kc = 1; kc < 4; ++kc) {                                       \
            _Pragma("unroll")                                                  \
            for (int mt = 0; mt < 8; ++mt)                                     \
                acc[mt] = __builtin_amdgcn_mfma_f32_16x16x32_bf16(ea[mt][kc], fr[kc], acc[mt], 0, 0, 0); \
        }                                                                      \
    }

// ---- FAC per-step body (unchanged).
#define FAC_STEP(t_, k_)                                                       \
    {                                                                          \
        const int t = (t_);                                                    \
        const int d = ((k_) + 7) & 7;                                          \
        float e0 = em[d][0], e1 = em[d][1], e2 = em[d][2], e3 = em[d][3];      \
        int tn = t + 8; if (tn > Tt - 1) tn = Tt - 1;                          \
        const float* xrow = xb + (size_t)tn * Nn;                              \
        em[d][0] = xrow[tgi[0]]; em[d][1] = xrow[tgi[1]];                      \
        em[d][2] = xrow[tgi[2]]; em[d][3] = xrow[tgi[3]];                      \
        float bup = __shfl_up(bt[3], 1);                                       \
        float prev0 = (lane == 0) ? NEGF : bup;                                \
        float nb[4];                                                           \
        {                                                                      \
            float aa = bt[0] + st[0], bb = prev0 + ntr[0];                     \
            float hi = fmaxf(aa, bb), lo = fminf(aa, bb);                      \
            nb[0] = e0 + hi + __logf(1.0f + __expf(lo - hi));                  \
        }                                                                      \
        {                                                                      \
            float aa = bt[1] + st[1], bb = bt[0] + ntr[1];                     \
            float hi = fmaxf(aa, bb), lo = fminf(aa, bb);                      \
            nb[1] = e1 + hi + __logf(1.0f + __expf(lo - hi));                  \
        }                                                                      \
        {                                                                      \
            float aa = bt[2] + st[2], bb = bt[1] + ntr[2];                     \
            float hi = fmaxf(aa, bb), lo = fminf(aa, bb);                      \
            nb[2] = e2 + hi + __logf(1.0f + __expf(lo - hi));                  \
        }                                                                      \
        {                                                                      \
            float aa = bt[3] + st[3], bb = bt[2] + ntr[3];                     \
            float hi = fmaxf(aa, bb), lo = fminf(aa, bb);                      \
            nb[3] = e3 + hi + __logf(1.0f + __expf(lo - hi));                  \
        }                                                                      \
        if (t < len) {                                                         \
            bt[0] = nb[0]; bt[1] = nb[1]; bt[2] = nb[2]; bt[3] = nb[3];        \
        }                                                                      \
    }

// Wp[((t*8 + wv)*8 + mt)*64 + lanep]*4 + r = exp(x[b][t][s] - 9),
//   b = wv*16 + (lanep&15), s = 32*(lanep>>4) + 4*mt + r.
// OUTPUT-linear (writes fully coalesced); reads are 16B pieces of x rows —
// the 4 waves of a block (mt..mt+3, same t,wv) cover each 64B line fully via L1.
// Round-2's input-linear version scattered WRITES 16KB apart: ~125us -> ~30us.
__global__ __launch_bounds__(256) void exp_w_kernel(const float* __restrict__ x,
                                                    float* __restrict__ w) {
    const int nf4 = Bb * Tt * Nn / 4;
    const int stride = gridDim.x * 256;
    for (int f = blockIdx.x * 256 + threadIdx.x; f < nf4; f += stride) {
        const int lanep = f & 63;
        const int mt    = (f >> 6) & 7;
        const int wv    = (f >> 9) & 7;
        const int t     = f >> 12;
        const int b     = (wv << 4) + (lanep & 15);
        const int s     = ((lanep >> 4) << 5) + (mt << 2);
        f32x4 v = *(const f32x4*)(x + ((size_t)b * Tt + t) * Nn + s);
        f32x4 r;
        r[0] = __expf(v[0] - D9); r[1] = __expf(v[1] - D9);
        r[2] = __expf(v[2] - D9); r[3] = __expf(v[3] - D9);
        *(f32x4*)(w + 4 * (size_t)f) = r;
    }
}

// blocks 0..7:  q0 = FCC wave (16 batches; sole wave on its SIMD), q1..3 = FAC
// blocks 8..33: 4 FAC waves each
template <bool PRE>
__global__ __launch_bounds__(256, 1) void asg_main(
    const float* __restrict__ trans, const float* __restrict__ x,
    const float* __restrict__ Wp,
    const int* __restrict__ targets, const int* __restrict__ ilen,
    const int* __restrict__ tlen,
    float* __restrict__ fcc_out, float* __restrict__ fac_out)
{
    const int tid  = threadIdx.x;
    const int q    = tid >> 6;
    const int lane = tid & 63;

    if (blockIdx.x < 8 && q == 0) {
        // ================= FCC (wave-synchronous, no LDS, no barriers) =========
        const int h  = lane >> 4;       // lane group: owns states 32h..32h+31
        const int cc = lane & 15;       // batch column within wave
        const int wv = blockIdx.x;      // 0..7
        const int b  = (wv << 4) + cc;
        const int len = ilen[b];

        constexpr int TSTR = PRE ? 16384 : Nn;   // floats per t-step in source
        constexpr int MSTR = PRE ? 256 : 4;      // floats per mt in source
        const float* wbase = PRE ? (Wp + (size_t)wv * 2048 + (lane << 2))
                                 : (x + (size_t)b * (Tt * Nn) + 32 * h);

        // E A-frags, state-permuted: ea[mt][kc][jj] = exp(trans[srow][scol]),
        //   srow = 32*(cc>>2) + 4*mt + (cc&3)   (M-index permutation)
        //   scol = 32*h + 8*kc + jj             (K-index permutation)
        short8 ea[8][4];
        #pragma unroll
        for (int mt = 0; mt < 8; ++mt) {
            const int srow = 32 * (cc >> 2) + 4 * mt + (cc & 3);
            const float* tr = trans + (size_t)srow * Nn + 32 * h;
            #pragma unroll
            for (int kc = 0; kc < 4; ++kc) {
                short8 v;
                #pragma unroll
                for (int jj = 0; jj < 8; ++jj)
                    v[jj] = bf16b(__expf(tr[8 * kc + jj]));
                ea[mt][kc] = v;
            }
        }

        f32x4 acc[8];       // E*u, slot (mt,r) = state 32h+4mt+r, col = batch cc
        f32x4 xs[4][8];     // w ring, depth 4 (static indices only)
        float c = 0.f, rm = 1.0f, sfin = 1.0f, cfin = 0.f;

        {   // t = 0: u0 = exp(x0 - 9); acc = E*u0
            float p0[8][4];
            #pragma unroll
            for (int mt = 0; mt < 8; ++mt) {
                f32x4 v = *(const f32x4*)(wbase + mt * MSTR);
                p0[mt][0] = WV(v[0]); p0[mt][1] = WV(v[1]);
                p0[mt][2] = WV(v[2]); p0[mt][3] = WV(v[3]);
            }
            short8 fr0[4];
            #pragma unroll
            for (int kc = 0; kc < 4; ++kc) {
                union { short8 s8; unsigned int u[4]; } F;
                F.u[0] = cvt_pk_bf16(p0[2*kc][0],   p0[2*kc][1]);
                F.u[1] = cvt_pk_bf16(p0[2*kc][2],   p0[2*kc][3]);
                F.u[2] = cvt_pk_bf16(p0[2*kc+1][0], p0[2*kc+1][1]);
                F.u[3] = cvt_pk_bf16(p0[2*kc+1][2], p0[2*kc+1][3]);
                fr0[kc] = F.s8;
            }
            const f32x4 zz = {0.f, 0.f, 0.f, 0.f};
            #pragma unroll
            for (int mt = 0; mt < 8; ++mt)
                acc[mt] = __builtin_amdgcn_mfma_f32_16x16x32_bf16(ea[mt][0], fr0[0], zz, 0, 0, 0);
            #pragma unroll
            for (int kc = 1; kc < 4; ++kc) {
                #pragma unroll
                for (int mt = 0; mt < 8; ++mt)
                    acc[mt] = __builtin_amdgcn_mfma_f32_16x16x32_bf16(ea[mt][kc], fr0[kc], acc[mt], 0, 0, 0);
            }
        }
        // preload ring rows 1..4 into slots 1,2,3,0
        #pragma unroll
        for (int k = 1; k <= 4; ++k) {
            const float* rr = wbase + (size_t)k * TSTR;
            #pragma unroll
            for (int mt = 0; mt < 8; ++mt)
                xs[k & 3][mt] = *(const f32x4*)(rr + mt * MSTR);
        }

        // steps t = 1..7, then 127 chunks of 8 (t = 8..1023)
        #pragma unroll
        for (int k = 1; k < 8; ++k) FCC_STEP(k, k)
        for (int tb = 8; tb < Tt; tb += 8) {
            #pragma unroll
            for (int k = 0; k < 8; ++k) FCC_STEP(tb + k, k)
        }

        if (lane < 16)
            fcc_out[(wv << 4) + lane] = cfin + D9 * (float)len + __logf(sfin);
    } else {
        // ================= FAC (1 wave per batch, no barriers) =================
        const int fid = (blockIdx.x < 8) ? (104 + blockIdx.x * 3 + (q - 1))
                                         : (((blockIdx.x - 8) << 2) + q);
        const int b   = fid;
        const int len = ilen[b];
        const int tl  = tlen[b];
        const float* xb = x + (size_t)b * Tt * Nn;

        int   tgi[4];
        float st[4], ntr[4], bt[4];
        #pragma unroll
        for (int r = 0; r < 4; ++r) {
            const int s = (lane << 2) + r;
            const int tgv = targets[b * Ss + s];
            const int pg  = (s == 0) ? tgv : targets[b * Ss + s - 1];
            tgi[r] = tgv;
            st[r]  = trans[tgv * Nn + tgv];
            ntr[r] = trans[tgv * Nn + pg];
            bt[r]  = (s == 0) ? xb[tgv] : NEGF;
        }
        // em ring depth 8; em[(k-1)&7] = x[k] for k=1..8 (constant indices)
        float em[8][4];
        #pragma unroll
        for (int k = 1; k <= 8; ++k) {
            int tt = k; if (tt > Tt - 1) tt = Tt - 1;
            const float* xrow = xb + (size_t)tt * Nn;
            em[(k - 1) & 7][0] = xrow[tgi[0]];
            em[(k - 1) & 7][1] = xrow[tgi[1]];
            em[(k - 1) & 7][2] = xrow[tgi[2]];
            em[(k - 1) & 7][3] = xrow[tgi[3]];
        }

        #pragma unroll
        for (int k = 1; k < 8; ++k) FAC_STEP(k, k)
        for (int tb = 8; tb < Tt; tb += 8) {
            #pragma unroll
            for (int k = 0; k < 8; ++k) FAC_STEP(tb + k, k)
        }

        #pragma unroll
        for (int r = 0; r < 4; ++r)
            if ((lane << 2) + r == tl - 1) fac_out[b] = bt[r];
    }
}

__global__ __launch_bounds__(128) void reduce_kernel(const float* __restrict__ fcc,
                                                     const float* __restrict__ fac,
                                                     float* __restrict__ out) {
    __shared__ float r2[2];
    int tid = threadIdx.x;
    float v = fcc[tid] - fac[tid];
    #pragma unroll
    for (int o = 32; o > 0; o >>= 1) v += __shfl_xor(v, o);
    if ((tid & 63) == 0) r2[tid >> 6] = v;
    __syncthreads();
    if (tid == 0) out[0] = (r2[0] + r2[1]) * (1.0f / Bb);
}

extern "C" void kernel_launch(void* const* d_in, const int* in_sizes, int n_in,
                              void* d_out, int out_size, void* d_ws, size_t ws_size,
                              hipStream_t stream) {
    const float* trans   = (const float*)d_in[0];
    const float* x       = (const float*)d_in[1];
    const int*   targets = (const int*)d_in[2];
    const int*   ilen    = (const int*)d_in[3];
    const int*   tlen    = (const int*)d_in[4];
    float* out = (float*)d_out;

    float* fcc = (float*)d_ws;                       // B floats
    float* fac = fcc + Bb;                           // B floats
    float* Wp  = (float*)((char*)d_ws + 2048);       // B*T*N floats (if it fits)

    const size_t wbytes = (size_t)Bb * Tt * Nn * sizeof(float);
    const bool pre = ws_size >= wbytes + 2048;

    if (pre) {
        exp_w_kernel<<<2048, 256, 0, stream>>>(x, Wp);
        asg_main<true><<<34, 256, 0, stream>>>(trans, x, Wp, targets, ilen, tlen, fcc, fac);
    } else {
        asg_main<false><<<34, 256, 0, stream>>>(trans, x, x, targets, ilen, tlen, fcc, fac);
    }
    reduce_kernel<<<1, 128, 0, stream>>>(fcc, fac, out);
}

// Round 4
// 389.880 us; speedup vs baseline: 2.6994x; 1.7508x over previous
//
#include <hip/hip_runtime.h>
#include <hip/hip_bf16.h>

#define Bb 128
#define Tt 1024
#define Nn 128
#define Ss 256
#define NEGF (-1e30f)
#define D9 9.0f   // fixed log-domain shift per active step (absorbed via c at the end)

typedef __attribute__((ext_vector_type(8))) short short8;  // 8 bf16 (4 VGPRs) — MFMA A/B frag
typedef __attribute__((ext_vector_type(4))) float f32x4;   // MFMA C/D frag

__device__ __forceinline__ short bf16b(float f) {
    __hip_bfloat16 h = __float2bfloat16(f);
    return *reinterpret_cast<short*>(&h);
}

// Single-instruction packed f32->bf16 (RNE).
__device__ __forceinline__ unsigned int cvt_pk_bf16(float lo, float hi) {
    unsigned int r;
    asm("v_cvt_pk_bf16_f32 %0, %1, %2" : "=v"(r) : "v"(lo), "v"(hi));
    return r;
}

// Raw workgroup barrier draining ONLY LDS (lgkmcnt), not vmcnt: the register
// ring prefetch loads stay in flight across the barrier (round-0-verified).
#define LDS_BARRIER() asm volatile("s_waitcnt lgkmcnt(0)\n\ts_barrier" ::: "memory")

// ---- FCC per-step body: 4-wave M-split (wave q owns states 32q..32q+31).
// Rationale (rounds 2/3 null result): ONE wave issues MFMA at only ~40cy each
// => 32 MFMA/step on one SIMD = ~1300cy/step regardless of staging. Splitting
// M over 4 waves/4 SIMDs cuts that to 8 MFMA/wave (~200cy overlapped), at the
// cost of one LDS u-exchange + lgkm-barrier per step (~180cy) — net ~2.5x.
// Freeze: one-shot snapshot at t==len-1 (per-column; garbage afterward stays
// bounded via renorm and confined to its batch column).
#define FCC_STEP(t_, k_)                                                       \
    {                                                                          \
        const int t = (t_);                                                    \
        const int sl = (k_) & 3;  /* compile-time ring slot */                 \
        f32x4 w0 = xs[sl][0], w1 = xs[sl][1];                                  \
        if (!PRE) {                                                            \
            w0[0] = __expf(w0[0] - D9); w0[1] = __expf(w0[1] - D9);            \
            w0[2] = __expf(w0[2] - D9); w0[3] = __expf(w0[3] - D9);            \
            w1[0] = __expf(w1[0] - D9); w1[1] = __expf(w1[1] - D9);            \
            w1[2] = __expf(w1[2] - D9); w1[3] = __expf(w1[3] - D9);            \
        }                                                                      \
        { /* refill ring slot sl with w-row t+4 (first use 4 steps away) */    \
            int tn = t + 4; if (tn > Tt - 1) tn = Tt - 1;                      \
            const float* gb = wbase + (size_t)tn * TSTR;                       \
            xs[sl][0] = *(const f32x4*)(gb);                                   \
            xs[sl][1] = *(const f32x4*)(gb + MSTR);                            \
        }                                                                      \
        const short* up = &ut[(t - 1) & 1][g][0] + quad * 8;                   \
        short8 bf0 = *(const short8*)(up);                                     \
        short8 bf1 = *(const short8*)(up + 32);                                \
        short8 bf2 = *(const short8*)(up + 64);                                \
        short8 bf3 = *(const short8*)(up + 96);                                \
        f32x4 a0p = {0.f, 0.f, 0.f, 0.f}, a0q = {0.f, 0.f, 0.f, 0.f};          \
        f32x4 a1p = {0.f, 0.f, 0.f, 0.f}, a1q = {0.f, 0.f, 0.f, 0.f};          \
        a0p = __builtin_amdgcn_mfma_f32_16x16x32_bf16(ea[0][0], bf0, a0p, 0, 0, 0); \
        a1p = __builtin_amdgcn_mfma_f32_16x16x32_bf16(ea[1][0], bf0, a1p, 0, 0, 0); \
        a0q = __builtin_amdgcn_mfma_f32_16x16x32_bf16(ea[0][2], bf2, a0q, 0, 0, 0); \
        a1q = __builtin_amdgcn_mfma_f32_16x16x32_bf16(ea[1][2], bf2, a1q, 0, 0, 0); \
        a0p = __builtin_amdgcn_mfma_f32_16x16x32_bf16(ea[0][1], bf1, a0p, 0, 0, 0); \
        a1p = __builtin_amdgcn_mfma_f32_16x16x32_bf16(ea[1][1], bf1, a1p, 0, 0, 0); \
        a0q = __builtin_amdgcn_mfma_f32_16x16x32_bf16(ea[0][3], bf3, a0q, 0, 0, 0); \
        a1q = __builtin_amdgcn_mfma_f32_16x16x32_bf16(ea[1][3], bf3, a1q, 0, 0, 0); \
        if ((k_) == 0) { /* renorm apply: wred written at k==7, post-barrier */\
            float m = fmaxf(fmaxf(wred[0][g], wred[1][g]),                     \
                            fmaxf(wred[2][g], wred[3][g]));                    \
            float invm = 1.0f / m;                                             \
            c += __logf(m);                                                    \
            w0 *= invm; w1 *= invm;                                            \
        }                                                                      \
        f32x4 un0 = w0 * (a0p + a0q);                                          \
        f32x4 un1 = w1 * (a1p + a1q);                                          \
        if (t == len - 1) { /* snapshot: 4 quad-lanes of a column share len */ \
            float s = (un0[0] + un0[1]) + (un0[2] + un0[3])                    \
                    + (un1[0] + un1[1]) + (un1[2] + un1[3]);                   \
            s += __shfl_xor(s, 16);                                            \
            s += __shfl_xor(s, 32);                                            \
            sfin = s; cfin = c;                                                \
        }                                                                      \
        {                                                                      \
            uint2 o0, o1;                                                      \
            o0.x = cvt_pk_bf16(un0[0], un0[1]); o0.y = cvt_pk_bf16(un0[2], un0[3]); \
            o1.x = cvt_pk_bf16(un1[0], un1[1]); o1.y = cvt_pk_bf16(un1[2], un1[3]); \
            *reinterpret_cast<uint2*>(&ut[t & 1][g][j0_]) = o0;                \
            *reinterpret_cast<uint2*>(&ut[t & 1][g][j0_ + 16]) = o1;           \
        }                                                                      \
        if ((k_) == 7) { /* renorm measure (unconditional; garbage harmless) */\
            float mm = fmaxf(fmaxf(un0[0], un0[1]), fmaxf(un0[2], un0[3]));    \
            mm = fmaxf(mm, fmaxf(fmaxf(un1[0], un1[1]), fmaxf(un1[2], un1[3])));\
            mm = fmaxf(mm, __shfl_xor(mm, 16));                                \
            mm = fmaxf(mm, __shfl_xor(mm, 32));                                \
            if (lane < 16) wred[q][lane] = mm;                                 \
        }                                                                      \
        LDS_BARRIER();                                                         \
    }

// ---- FAC per-step body (unchanged).
#define FAC_STEP(t_, k_)                                                       \
    {                                                                          \
        const int t = (t_);                                                    \
        const int d = ((k_) + 7) & 7;                                          \
        float e0 = em[d][0], e1 = em[d][1], e2 = em[d][2], e3 = em[d][3];      \
        int tn = t + 8; if (tn > Tt - 1) tn = Tt - 1;                          \
        const float* xrow = xb + (size_t)tn * Nn;                              \
        em[d][0] = xrow[tgi[0]]; em[d][1] = xrow[tgi[1]];                      \
        em[d][2] = xrow[tgi[2]]; em[d][3] = xrow[tgi[3]];                      \
        float bup = __shfl_up(bt[3], 1);                                       \
        float prev0 = (lane == 0) ? NEGF : bup;                                \
        float nb[4];                                                           \
        {                                                                      \
            float aa = bt[0] + st[0], bb = prev0 + ntr[0];                     \
            float hi = fmaxf(aa, bb), lo = fminf(aa, bb);                      \
            nb[0] = e0 + hi + __logf(1.0f + __expf(lo - hi));                  \
        }                                                                      \
        {                                                                      \
            float aa = bt[1] + st[1], bb = bt[0] + ntr[1];                     \
            float hi = fmaxf(aa, bb), lo = fminf(aa, bb);                      \
            nb[1] = e1 + hi + __logf(1.0f + __expf(lo - hi));                  \
        }                                                                      \
        {                                                                      \
            float aa = bt[2] + st[2], bb = bt[1] + ntr[2];                     \
            float hi = fmaxf(aa, bb), lo = fminf(aa, bb);                      \
            nb[2] = e2 + hi + __logf(1.0f + __expf(lo - hi));                  \
        }                                                                      \
        {                                                                      \
            float aa = bt[3] + st[3], bb = bt[2] + ntr[3];                     \
            float hi = fmaxf(aa, bb), lo = fminf(aa, bb);                      \
            nb[3] = e3 + hi + __logf(1.0f + __expf(lo - hi));                  \
        }                                                                      \
        if (t < len) {                                                         \
            bt[0] = nb[0]; bt[1] = nb[1]; bt[2] = nb[2]; bt[3] = nb[3];        \
        }                                                                      \
    }

// Wm[(((t*8 + wv)*4 + q)*2 + mt)*64 + l]*4 + r = exp(x[b][t][j] - 9),
//   b = 16*wv + (l&15), j = 32*q + 16*mt + 4*(l>>4) + r.
// Each FCC wave's per-step load = 2 x (64 lanes x 16B contiguous). Writes here
// are fully coalesced; reads cover x rows in full 64B lines across the block.
__global__ __launch_bounds__(256) void exp_w_kernel(const float* __restrict__ x,
                                                    float* __restrict__ w) {
    const int nf4 = Bb * Tt * Nn / 4;
    const int stride = gridDim.x * 256;
    for (int f = blockIdx.x * 256 + threadIdx.x; f < nf4; f += stride) {
        const int l    = f & 63;
        const int mt   = (f >> 6) & 1;
        const int qq   = (f >> 7) & 3;
        const int wv   = (f >> 9) & 7;
        const int t    = f >> 12;
        const int b    = (wv << 4) + (l & 15);
        const int j    = (qq << 5) + (mt << 4) + ((l >> 4) << 2);
        f32x4 v = *(const f32x4*)(x + ((size_t)b * Tt + t) * Nn + j);
        f32x4 r;
        r[0] = __expf(v[0] - D9); r[1] = __expf(v[1] - D9);
        r[2] = __expf(v[2] - D9); r[3] = __expf(v[3] - D9);
        *(f32x4*)(w + 4 * (size_t)f) = r;
    }
}

// blocks 0..7:  FCC, 16 batches each, 4 waves M-split over states
// blocks 8..39: FAC, 4 batches each (1 wave per batch, wave-synchronous)
template <bool PRE>
__global__ __launch_bounds__(256, 1) void asg_main(
    const float* __restrict__ trans, const float* __restrict__ x,
    const float* __restrict__ Wm,
    const int* __restrict__ targets, const int* __restrict__ ilen,
    const int* __restrict__ tlen,
    float* __restrict__ fcc_out, float* __restrict__ fac_out)
{
    __shared__ __align__(16) short ut[2][16][136];  // pad 8: 272B row, 2-way banks
    __shared__ float wred[4][16];

    const int tid  = threadIdx.x;
    const int q    = tid >> 6;
    const int lane = tid & 63;

    if (blockIdx.x < 8) {
        // ================= FCC (4-wave M-split) =================
        const int g    = lane & 15;     // batch column
        const int quad = lane >> 4;
        const int wv   = blockIdx.x;
        const int b    = (wv << 4) + g;
        const int len  = ilen[b];
        const int j0_  = 32 * q + 4 * quad;

        constexpr int TSTR = PRE ? 16384 : Nn;   // floats per t-step in source
        constexpr int MSTR = PRE ? 64 * 4 : 16;  // floats between mt=0 and mt=1
        const float* wbase = PRE
            ? (Wm + (size_t)(((wv << 2) + q) << 1) * 256 + (lane << 2))
            : (x + (size_t)b * (Tt * Nn) + 32 * q + 4 * quad);

        // E A-frags: wave q owns rows [32q, 32q+32) -> 2 M-tiles of 16.
        short8 ea[2][4];
        #pragma unroll
        for (int mt = 0; mt < 2; ++mt) {
            const float* tr = trans + (size_t)(32 * q + 16 * mt + g) * Nn + quad * 8;
            #pragma unroll
            for (int kc = 0; kc < 4; ++kc) {
                short8 v;
                #pragma unroll
                for (int jj = 0; jj < 8; ++jj)
                    v[jj] = bf16b(__expf(tr[kc * 32 + jj]));
                ea[mt][kc] = v;
            }
        }

        f32x4 xs[4][2];   // w ring, depth 4 (static indices only)
        float c = 0.f, sfin = 1.0f, cfin = 0.f;

        {   // t = 0: u0 = exp(x0 - 9) -> LDS (bf16)
            f32x4 v0 = *(const f32x4*)(wbase);
            f32x4 v1 = *(const f32x4*)(wbase + MSTR);
            if (!PRE) {
                v0[0]=__expf(v0[0]-D9); v0[1]=__expf(v0[1]-D9);
                v0[2]=__expf(v0[2]-D9); v0[3]=__expf(v0[3]-D9);
                v1[0]=__expf(v1[0]-D9); v1[1]=__expf(v1[1]-D9);
                v1[2]=__expf(v1[2]-D9); v1[3]=__expf(v1[3]-D9);
            }
            uint2 o0, o1;
            o0.x = cvt_pk_bf16(v0[0], v0[1]); o0.y = cvt_pk_bf16(v0[2], v0[3]);
            o1.x = cvt_pk_bf16(v1[0], v1[1]); o1.y = cvt_pk_bf16(v1[2], v1[3]);
            *reinterpret_cast<uint2*>(&ut[0][g][j0_]) = o0;
            *reinterpret_cast<uint2*>(&ut[0][g][j0_ + 16]) = o1;
        }
        // preload ring rows 1..4 into slots 1,2,3,0
        #pragma unroll
        for (int k = 1; k <= 4; ++k) {
            const float* rr = wbase + (size_t)k * TSTR;
            xs[k & 3][0] = *(const f32x4*)(rr);
            xs[k & 3][1] = *(const f32x4*)(rr + MSTR);
        }
        __syncthreads();   // setup barrier (once; full drain acceptable)

        // steps t = 1..7, then 127 chunks of 8 (t = 8..1023)
        #pragma unroll
        for (int k = 1; k < 8; ++k) FCC_STEP(k, k)
        for (int tb = 8; tb < Tt; tb += 8) {
            #pragma unroll
            for (int k = 0; k < 8; ++k) FCC_STEP(tb + k, k)
        }

        // cross-wave sum of the snapshotted partials
        if (lane < 16) wred[q][lane] = sfin;
        __syncthreads();
        if (q == 0 && lane < 16) {
            float tot = wred[0][lane] + wred[1][lane] + wred[2][lane] + wred[3][lane];
            fcc_out[(wv << 4) + lane] = cfin + D9 * (float)len + __logf(tot);
        }
    } else {
        // ================= FAC (1 wave per batch, no barriers) =================
        const int b   = ((blockIdx.x - 8) << 2) + q;
        const int len = ilen[b];
        const int tl  = tlen[b];
        const float* xb = x + (size_t)b * Tt * Nn;

        int   tgi[4];
        float st[4], ntr[4], bt[4];
        #pragma unroll
        for (int r = 0; r < 4; ++r) {
            const int s = (lane << 2) + r;
            const int tgv = targets[b * Ss + s];
            const int pg  = (s == 0) ? tgv : targets[b * Ss + s - 1];
            tgi[r] = tgv;
            st[r]  = trans[tgv * Nn + tgv];
            ntr[r] = trans[tgv * Nn + pg];
            bt[r]  = (s == 0) ? xb[tgv] : NEGF;
        }
        // em ring depth 8; em[(k-1)&7] = x[k] for k=1..8 (constant indices)
        float em[8][4];
        #pragma unroll
        for (int k = 1; k <= 8; ++k) {
            int tt = k; if (tt > Tt - 1) tt = Tt - 1;
            const float* xrow = xb + (size_t)tt * Nn;
            em[(k - 1) & 7][0] = xrow[tgi[0]];
            em[(k - 1) & 7][1] = xrow[tgi[1]];
            em[(k - 1) & 7][2] = xrow[tgi[2]];
            em[(k - 1) & 7][3] = xrow[tgi[3]];
        }

        #pragma unroll
        for (int k = 1; k < 8; ++k) FAC_STEP(k, k)
        for (int tb = 8; tb < Tt; tb += 8) {
            #pragma unroll
            for (int k = 0; k < 8; ++k) FAC_STEP(tb + k, k)
        }

        #pragma unroll
        for (int r = 0; r < 4; ++r)
            if ((lane << 2) + r == tl - 1) fac_out[b] = bt[r];
    }
}

__global__ __launch_bounds__(128) void reduce_kernel(const float* __restrict__ fcc,
                                                     const float* __restrict__ fac,
                                                     float* __restrict__ out) {
    __shared__ float r2[2];
    int tid = threadIdx.x;
    float v = fcc[tid] - fac[tid];
    #pragma unroll
    for (int o = 32; o > 0; o >>= 1) v += __shfl_xor(v, o);
    if ((tid & 63) == 0) r2[tid >> 6] = v;
    __syncthreads();
    if (tid == 0) out[0] = (r2[0] + r2[1]) * (1.0f / Bb);
}

extern "C" void kernel_launch(void* const* d_in, const int* in_sizes, int n_in,
                              void* d_out, int out_size, void* d_ws, size_t ws_size,
                              hipStream_t stream) {
    const float* trans   = (const float*)d_in[0];
    const float* x       = (const float*)d_in[1];
    const int*   targets = (const int*)d_in[2];
    const int*   ilen    = (const int*)d_in[3];
    const int*   tlen    = (const int*)d_in[4];
    float* out = (float*)d_out;

    float* fcc = (float*)d_ws;                       // B floats
    float* fac = fcc + Bb;                           // B floats
    float* Wm  = (float*)((char*)d_ws + 2048);       // B*T*N floats (if it fits)

    const size_t wbytes = (size_t)Bb * Tt * Nn * sizeof(float);
    const bool pre = ws_size >= wbytes + 2048;

    if (pre) {
        exp_w_kernel<<<2048, 256, 0, stream>>>(x, Wm);
        asg_main<true><<<40, 256, 0, stream>>>(trans, x, Wm, targets, ilen, tlen, fcc, fac);
    } else {
        asg_main<false><<<40, 256, 0, stream>>>(trans, x, x, targets, ilen, tlen, fcc, fac);
    }
    reduce_kernel<<<1, 128, 0, stream>>>(fcc, fac, out);
}